// Round 9
// baseline (168.849 us; speedup 1.0000x reference)
//
#include <hip/hip_runtime.h>
#include <math.h>

// Problem constants (fixed by setup_inputs)
#define BATCH 8
#define HI 512
#define WI 512
#define HO 256
#define WO 256
#define PLANE (HI*WI)          // 262144 per channel
#define OPIX (HO*WO)           // 65536 output pixels per batch
// R9: no LDS, no barriers. 1 pixel/thread. Batched streaming loads up front,
// image corners gathered directly from global (per-batch band ~31 KB -> L1/L2 hot).

__global__ __launch_bounds__(256) void downsampler_kernel(
    const float* __restrict__ images,
    const float* __restrict__ kernels,
    const float* __restrict__ offx,
    const float* __restrict__ offy,
    float* __restrict__ out)
{
    const int blk  = blockIdx.x;          // 2048 blocks
    const int b    = blk >> 8;            // batch
    const int ihx  = (blk >> 2) & 63;     // ih-tile (4 rows)
    const int w0   = (blk & 3) << 6;      // iw-tile base (64 cols)
    const int tid  = threadIdx.x;
    const int lane = tid & 63;
    const int iw   = w0 + lane;
    const int ih   = (ihx << 2) + (tid >> 6);   // wave-uniform

    const float* imb   = images  + (size_t)b * 3 * PLANE;
    const float* offxb = offx    + (size_t)b * 9 * OPIX;
    const float* offyb = offy    + (size_t)b * 9 * OPIX;
    const float* kernb = kernels + (size_t)b * 9 * OPIX;

    const int pl   = ih * WO + iw;
    const int pix2 = pl & (OPIX / 2 - 1);  // float2 index of scrambled pair (2pl, 2pl+1)

    // ==== PHASE 1: issue all 45 streaming loads back-to-back (MLP) ====
    float  ox_[9], oy_[9], kv_[9];
    float2 sx_[9], sy_[9];
    #pragma unroll
    for (int k = 0; k < 9; ++k) {
        ox_[k] = offxb[k * OPIX + pl];
        oy_[k] = offyb[k * OPIX + pl];
        kv_[k] = kernb[k * OPIX + pl];
        sx_[k] = ((const float2*)(offxb + k * OPIX))[pix2];
        sy_[k] = ((const float2*)(offyb + k * OPIX))[pix2];
    }

    // ==== PHASE 2: per-tap gather (global, cache-hot band) + compute ====
    const bool flip = (ih < 128);          // wave-uniform
    const float uu_own = (float)iw + 0.5f;
    const float uu_s0  = (float)((2 * iw) & 255) + 0.5f;
    const float uu_s1  = uu_s0 + 1.0f;     // no wrap: (2iw)&255 is even <= 254

    float acc0 = 0.f, acc1 = 0.f, acc2 = 0.f;

    #pragma unroll
    for (int k = 0; k < 9; ++k) {
        // ---- own coords -> corner addresses ----
        const float kxf = (float)(k / 3);
        const float kyf = (float)(k - 3 * (k / 3));
        const float cx = ((ox_[k] + 1.5f) + kxf) + uu_own;   // reference fp32 op order
        const float cy = ((oy_[k] + 1.5f) + kyf) + uu_own;
        const int x0 = (int)floorf(cx);        // row in [iw+2, iw+5], no clamp needed
        const int y0 = (int)floorf(cy);        // col in [iw+2, iw+5]

        // 12 corner-channel gathers straight from global (band is L1/L2-resident)
        const float* cbase = imb + x0 * WI + y0;
        const float Ia0 = cbase[0],              Ib0 = cbase[1];
        const float Ic0 = cbase[WI],             Id0 = cbase[WI + 1];
        const float Ia1 = cbase[PLANE],          Ib1 = cbase[PLANE + 1];
        const float Ic1 = cbase[PLANE + WI],     Id1 = cbase[PLANE + WI + 1];
        const float Ia2 = cbase[2 * PLANE],      Ib2 = cbase[2 * PLANE + 1];
        const float Ic2 = cbase[2 * PLANE + WI], Id2 = cbase[2 * PLANE + WI + 1];

        // ---- scrambled weights for taps t=2k, 2k+1 ----
        const int ta = 2 * k, tb = 2 * k + 1;
        const int sel_a = (ta >= 9) ? 1 : 0;
        const int sel_b = (tb >= 9) ? 1 : 0;
        const int ks_a = ta - 9 * sel_a;
        const int ks_b = tb - 9 * sel_b;
        const float uu_a = sel_a ? uu_s1 : uu_s0;
        const float uu_b = sel_b ? uu_s1 : uu_s0;
        const float oxa  = sel_a ? sx_[ks_a].y : sx_[ks_a].x;
        const float oya  = sel_a ? sy_[ks_a].y : sy_[ks_a].x;
        const float oxb2 = sel_b ? sx_[ks_b].y : sx_[ks_b].x;
        const float oyb2 = sel_b ? sy_[ks_b].y : sy_[ks_b].x;
        const float kxa = (float)(ks_a / 3), kya = (float)(ks_a - 3 * (ks_a / 3));
        const float kxb = (float)(ks_b / 3), kyb = (float)(ks_b - 3 * (ks_b / 3));

        const float cxa = ((oxa + 1.5f) + kxa) + uu_a;    // reference fp32 op order
        const float cya = ((oya + 1.5f) + kya) + uu_a;
        const float cxb = ((oxb2 + 1.5f) + kxb) + uu_b;
        const float cyb = ((oyb2 + 1.5f) + kyb) + uu_b;
        const float fxa = cxa - floorf(cxa);   // exact (Sterbenz)
        const float fya = cya - floorf(cya);
        const float fxb = cxb - floorf(cxb);
        const float fyb = cyb - floorf(cyb);
        const float w0w = flip ? (1.0f - fxa) : fxa;   // wx[2k]
        const float w1w = flip ? (1.0f - fxb) : fxb;   // wx[2k+1]
        const float v0w = flip ? (1.0f - fya) : fya;   // wy[2k]
        const float v1w = flip ? (1.0f - fyb) : fyb;   // wy[2k+1]

        const float w0v0 = w0w * v0w, w1v0 = w1w * v0w;
        const float w0v1 = w0w * v1w, w1v1 = w1w * v1w;

        // scrambled channel/corner table
        const float p0 = w0v0 * Ib0 + w1v0 * Ic0 + w0v1 * Id1 + w1v1 * Ia2;
        const float p1 = w0v0 * Ia0 + w1v0 * Ib1 + w0v1 * Ic1 + w1v1 * Id2;
        const float p2 = w0v0 * Id0 + w1v0 * Ia1 + w0v1 * Ib2 + w1v1 * Ic2;

        acc0 += kv_[k] * p0;
        acc1 += kv_[k] * p1;
        acc2 += kv_[k] * p2;
    }

    // ---- softround(out * 255) via HW sin (input in revolutions) ----
    const float TWO_PI_INV = 0.15915494309189533577f;
    const size_t obase = ((size_t)b * OPIX + (size_t)pl) * 3;
    const float z0 = acc0 * 255.0f;
    const float z1 = acc1 * 255.0f;
    const float z2 = acc2 * 255.0f;
    const float r0s = z0 - rintf(z0);   // exact; sin(2*pi*z) = sin(2*pi*r)
    const float r1s = z1 - rintf(z1);
    const float r2s = z2 - rintf(z2);
    out[obase + 0] = z0 - __builtin_amdgcn_sinf(r0s) * TWO_PI_INV;
    out[obase + 1] = z1 - __builtin_amdgcn_sinf(r1s) * TWO_PI_INV;
    out[obase + 2] = z2 - __builtin_amdgcn_sinf(r2s) * TWO_PI_INV;
}

extern "C" void kernel_launch(void* const* d_in, const int* in_sizes, int n_in,
                              void* d_out, int out_size, void* d_ws, size_t ws_size,
                              hipStream_t stream) {
    const float* images  = (const float*)d_in[0];
    const float* kernels = (const float*)d_in[1];
    const float* offx    = (const float*)d_in[2];
    const float* offy    = (const float*)d_in[3];
    float* out = (float*)d_out;

    dim3 grid(BATCH * 64 * 4);   // 2048 blocks: (b, ih-tile of 4, iw-tile of 64)
    dim3 block(256);             // 1 pixel per thread, no LDS, no barriers
    hipLaunchKernelGGL(downsampler_kernel, grid, block, 0, stream,
                       images, kernels, offx, offy, out);
}

// Round 10
// 117.486 us; speedup vs baseline: 1.4372x; 1.4372x over previous
//
#include <hip/hip_runtime.h>
#include <math.h>

// Problem constants (fixed by setup_inputs)
#define BATCH 8
#define HI 512
#define WI 512
#define HO 256
#define WO 256
#define PLANE (HI*WI)          // 262144 per channel
#define OPIX (HO*WO)           // 65536 output pixels per batch
// Block: 4 waves = 4 ih-rows; each lane owns 2 consecutive iw (wave covers 128 cols).
// Own offsets/kern loads -> dwordx2; scrambled pair-runs (4 consecutive floats) -> dwordx4.
// k-loop unrolled only 3x: ~66 live floats -> no spill (R8 post-mortem).
#define LROWS 132              // image rows [w0+2, w0+134)
#define LQ 11                  // float4 per band row: 10 data + 1 pad

__device__ __forceinline__ float elem4(const float4 v, int i) {
    switch (i & 3) { case 0: return v.x; case 1: return v.y; case 2: return v.z; default: return v.w; }
}

__global__ __launch_bounds__(256) void downsampler_kernel(
    const float* __restrict__ images,
    const float* __restrict__ kernels,
    const float* __restrict__ offx,
    const float* __restrict__ offy,
    float* __restrict__ out)
{
    __shared__ float4 simg[LROWS * LQ];   // 23232 B

    const int blk  = blockIdx.x;          // 1024 blocks
    const int b    = blk >> 7;            // batch
    const int rem  = blk & 127;
    const int ihx  = rem >> 1;            // 4-row tile (0..63)
    const int w0   = (rem & 1) << 7;      // iw-tile base (0 or 128)
    const int tid  = threadIdx.x;
    const int lane = tid & 63;
    const int g    = tid >> 6;            // wave id = row within tile
    const int ih   = (ihx << 2) + g;
    const int iw0  = w0 + (lane << 1);    // first of 2 pixels
    const int pl0  = ih * WO + iw0;       // even

    // ---- Stage the 132x10 band as RGBX float4 into LDS ----
    // I(r, c, .) = simg[(r-(w0+2))*11 + (c-(r-4))], r in [w0+2, w0+134)
    {
        const float* imb = images + (size_t)b * 3 * PLANE;
        #pragma unroll
        for (int ii = 0; ii < 6; ++ii) {
            const int i = tid + ii * 256;
            if (i < LROWS * 10) {
                const int row = i / 10;
                const int col = i - row * 10;
                const int r = w0 + 2 + row;
                int c = r - 4 + col;
                c = c < 0 ? 0 : c;   // upper clamp provably inactive (c <= 266 < 512)
                const float* src = imb + r * WI + c;
                simg[row * LQ + col] = make_float4(src[0], src[PLANE], src[2 * PLANE], 0.0f);
            }
        }
    }
    __syncthreads();

    const bool flip = (ih < 128);          // wave-uniform
    const float* offxb = offx    + (size_t)b * 9 * OPIX;
    const float* offyb = offy    + (size_t)b * 9 * OPIX;
    const float* kernb = kernels + (size_t)b * 9 * OPIX;

    const int own2   = pl0 >> 1;                     // float2 index of own 2 pixels
    const int s4     = ((2 * pl0) & (OPIX - 1)) >> 2;// float4 index of scrambled 4-run
    const int c2base = (2 * iw0) & 255;              // source col base (may wrap +3)

    float acc[2][3] = {{0.f,0.f,0.f},{0.f,0.f,0.f}};

    #pragma unroll 3
    for (int k = 0; k < 9; ++k) {
        const int kd = k / 3;
        const float kxf = (float)kd;
        const float kyf = (float)(k - 3 * kd);
        const int ta = 2 * k, tb = 2 * k + 1;
        const int sel_a = (ta >= 9) ? 1 : 0;
        const int sel_b = (tb >= 9) ? 1 : 0;
        const int ks_a = ta - 9 * sel_a;
        const int ks_b = tb - 9 * sel_b;
        const int kda = ks_a / 3, kdb = ks_b / 3;
        const float kxa = (float)kda, kya = (float)(ks_a - 3 * kda);
        const float kxb = (float)kdb, kyb = (float)(ks_b - 3 * kdb);

        // ---- wide loads: 3 dwordx2 + 4 dwordx4 per tap (covers both pixels) ----
        const float2 ox2 = ((const float2*)(offxb + (size_t)k * OPIX))[own2];
        const float2 oy2 = ((const float2*)(offyb + (size_t)k * OPIX))[own2];
        const float2 kv2 = ((const float2*)(kernb + (size_t)k * OPIX))[own2];
        const float4 sxa = ((const float4*)(offxb + (size_t)ks_a * OPIX))[s4];
        const float4 sya = ((const float4*)(offyb + (size_t)ks_a * OPIX))[s4];
        const float4 sxb = ((const float4*)(offxb + (size_t)ks_b * OPIX))[s4];
        const float4 syb = ((const float4*)(offyb + (size_t)ks_b * OPIX))[s4];

        #pragma unroll
        for (int p = 0; p < 2; ++p) {
            // ---- own coords -> gather corners from LDS ----
            const float uu_own = (float)(iw0 + p) + 0.5f;
            const float oxv = p ? ox2.y : ox2.x;
            const float oyv = p ? oy2.y : oy2.x;
            const float cx = ((oxv + 1.5f) + kxf) + uu_own;   // reference fp32 op order
            const float cy = ((oyv + 1.5f) + kyf) + uu_own;
            const int x0 = (int)floorf(cx);        // row in [iw+2, iw+5]
            const int y0 = (int)floorf(cy);        // col in [iw+2, iw+5]
            const int rowrel = x0 - 2 - w0;        // [2*lane, 2*lane+6] < 132
            const int colq   = y0 - x0 + 4;        // [1, 7]
            const float4* qa = &simg[rowrel * LQ + (colq - 1)];
            const float4 Ia = qa[1];               // (x0,y0)
            const float4 Ib = qa[2];               // (x0,y1)
            const float4 Ic = qa[LQ];              // (x1,y0)
            const float4 Id = qa[LQ + 1];          // (x1,y1)

            // ---- scrambled weights: elements 2p+sel of the 4-run ----
            const int ea = 2 * p + sel_a;          // 0..3
            const int eb = 2 * p + sel_b;
            const float uua = (float)((c2base + ea) & 255) + 0.5f;
            const float uub = (float)((c2base + eb) & 255) + 0.5f;
            const float cxa = ((elem4(sxa, ea) + 1.5f) + kxa) + uua;
            const float cya = ((elem4(sya, ea) + 1.5f) + kya) + uua;
            const float cxb = ((elem4(sxb, eb) + 1.5f) + kxb) + uub;
            const float cyb = ((elem4(syb, eb) + 1.5f) + kyb) + uub;
            const float fxa = cxa - floorf(cxa);   // exact (Sterbenz)
            const float fya = cya - floorf(cya);
            const float fxb = cxb - floorf(cxb);
            const float fyb = cyb - floorf(cyb);
            const float w0w = flip ? (1.0f - fxa) : fxa;   // wx[2k]
            const float w1w = flip ? (1.0f - fxb) : fxb;   // wx[2k+1]
            const float v0w = flip ? (1.0f - fya) : fya;   // wy[2k]
            const float v1w = flip ? (1.0f - fyb) : fyb;   // wy[2k+1]

            const float w0v0 = w0w * v0w, w1v0 = w1w * v0w;
            const float w0v1 = w0w * v1w, w1v1 = w1w * v1w;

            // scrambled channel/corner table
            const float p0 = w0v0 * Ib.x + w1v0 * Ic.x + w0v1 * Id.y + w1v1 * Ia.z;
            const float p1 = w0v0 * Ia.x + w1v0 * Ib.y + w0v1 * Ic.y + w1v1 * Id.z;
            const float p2 = w0v0 * Id.x + w1v0 * Ia.y + w0v1 * Ib.z + w1v1 * Ic.z;

            const float kv = p ? kv2.y : kv2.x;
            acc[p][0] += kv * p0;
            acc[p][1] += kv * p1;
            acc[p][2] += kv * p2;
        }
    }

    // ---- softround(out * 255) + 3x dwordx2 coalesced stores ----
    const float TWO_PI_INV = 0.15915494309189533577f;
    float o[6];
    #pragma unroll
    for (int p = 0; p < 2; ++p) {
        #pragma unroll
        for (int ch = 0; ch < 3; ++ch) {
            const float z  = acc[p][ch] * 255.0f;
            const float rs = z - rintf(z);   // exact; sin(2*pi*z) = sin(2*pi*rs)
            o[p * 3 + ch] = z - __builtin_amdgcn_sinf(rs) * TWO_PI_INV;
        }
    }
    float2* o2 = (float2*)(out + ((size_t)b * OPIX + (size_t)pl0) * 3);  // 24B-aligned
    o2[0] = make_float2(o[0], o[1]);
    o2[1] = make_float2(o[2], o[3]);
    o2[2] = make_float2(o[4], o[5]);
}

extern "C" void kernel_launch(void* const* d_in, const int* in_sizes, int n_in,
                              void* d_out, int out_size, void* d_ws, size_t ws_size,
                              hipStream_t stream) {
    const float* images  = (const float*)d_in[0];
    const float* kernels = (const float*)d_in[1];
    const float* offx    = (const float*)d_in[2];
    const float* offy    = (const float*)d_in[3];
    float* out = (float*)d_out;

    dim3 grid(BATCH * 64 * 2);   // 1024 blocks: (b, 4-row tile, 128-col tile)
    dim3 block(256);             // 4 waves x 64 lanes, 2 px/lane
    hipLaunchKernelGGL(downsampler_kernel, grid, block, 0, stream,
                       images, kernels, offx, offy, out);
}